// Round 8
// baseline (51.040 us; speedup 1.0000x reference)
//
#include <hip/hip_runtime.h>

#define NB 8
#define NQ 4096   // h*w
#define NP 2048
#define FINF 3.402823466e38f

typedef float f2 __attribute__((ext_vector_type(2)));
typedef float f4 __attribute__((ext_vector_type(4)));

// VOP3P packed FMA: ALL operands are 64-bit register pairs (scalar src0 does not
// assemble; broadcasts are materialized as pairs — R5/R6 lessons: do NOT pack via
// op_sel, do NOT force VGPR caps; the allocator remat disaster costs 4.7x).
__device__ __forceinline__ f2 pk_fma(f2 a, f2 b, f2 c) {
    f2 d;
    asm("v_pk_fma_f32 %0, %1, %2, %3" : "=v"(d) : "v"(a), "v"(b), "v"(c));
    return d;
}
__device__ __forceinline__ float min3f(float a, float b, float c) {
    float d;
    asm("v_min3_f32 %0, %1, %2, %3" : "=v"(d) : "v"(a), "v"(b), "v"(c));
    return d;
}

// Single fused kernel: 512 blocks x 256 threads, 66 KB LDS -> 2 blocks/CU, all
// blocks co-resident. EXACTLY R4's main body (best measured: 20.45 us total),
// plus a last-block deterministic finish replacing the second launch.
//  blocks [0,256):   bp. b=blk>>5, pb=blk&31: owns 64 p; stages all 4096 y (2048 pairs).
//  blocks [256,512): bq. b=idx>>5, qb=idx&31: owns 128 q; stages all 2048 t (1024 pairs).
// Pair j in LDS: A[j]=(x0,x1,y0,y1), B[j]=(z0,z1,n0,n1), n = w^2-norm.
// pg owns 16 points (f2 broadcast pairs in regs), s = slice; interleaved pair index
// j*nSlices+s -> conflict-free ds_read_b128. Per 2 distances: 3 pk_fma + 1 min3
// (owned norm deferred to epilogue). Each block -> ONE complete partial sum.
__global__ __launch_bounds__(256) void chamfer_fused(const float* __restrict__ y,
                                                     const float* __restrict__ t,
                                                     const float* __restrict__ w,
                                                     float* __restrict__ blockSums,
                                                     int* __restrict__ cnt,
                                                     float* __restrict__ out)
{
    __shared__ f4 ldsA[2048];   // 32 KB
    __shared__ f4 ldsB[2048];   // 32 KB
    __shared__ f4 ldsQuad[128]; // owned: (-2w2c0, -2w2c1, -2w2c2, norm)
    __shared__ float wsum[2];
    __shared__ int lastFlag;
    __shared__ double redd[4];

    const int tid = threadIdx.x;
    const int blk = blockIdx.x;
    const float w0 = w[0]*w[0], w1 = w[1]*w[1], w2 = w[2]*w[2];

    int nOwn, nSlices, pg, s;

    if (blk < 256) {
        // ---- bp: own 64 p, stage 4096 y-points (2048 pairs) ----
        nOwn = 64; nSlices = 64; pg = tid & 3; s = tid >> 2;
        const int b = blk >> 5, pb = blk & 31;
        const float* yb = y + (size_t)b * 3 * NQ;
        const f2* xs = (const f2*)yb;
        const f2* ys = (const f2*)(yb + NQ);
        const f2* zs = (const f2*)(yb + 2*NQ);
        for (int i = tid; i < 2048; i += 256) {
            const f2 xp = xs[i], yp = ys[i], zp = zs[i];
            const float n0 = w0*xp.x*xp.x + w1*yp.x*yp.x + w2*zp.x*zp.x;
            const float n1 = w0*xp.y*xp.y + w1*yp.y*yp.y + w2*zp.y*zp.y;
            f4 va = {xp.x, xp.y, yp.x, yp.y};
            f4 vb = {zp.x, zp.y, n0, n1};
            ldsA[i] = va; ldsB[i] = vb;
        }
        if (tid < 64) {
            const float* tp = t + ((size_t)b * NP + pb*64 + tid) * 3;
            const float t0 = tp[0], t1 = tp[1], t2 = tp[2];
            f4 q = {-2.f*w0*t0, -2.f*w1*t1, -2.f*w2*t2,
                    w0*t0*t0 + w1*t1*t1 + w2*t2*t2};
            ldsQuad[tid] = q;
        }
    } else {
        // ---- bq: own 128 q, stage 2048 t-points (1024 pairs) ----
        nOwn = 128; nSlices = 32; pg = tid & 7; s = tid >> 3;
        const int idx = blk - 256;
        const int b = idx >> 5, qb = idx & 31;
        const float* tb = t + (size_t)b * NP * 3;
        for (int i = tid; i < 1024; i += 256) {
            const f2* tp2 = (const f2*)(tb + i*6);
            const f2 u0 = tp2[0], u1 = tp2[1], u2 = tp2[2];
            // pt0=(u0.x,u0.y,u1.x)  pt1=(u1.y,u2.x,u2.y)
            const float n0 = w0*u0.x*u0.x + w1*u0.y*u0.y + w2*u1.x*u1.x;
            const float n1 = w0*u1.y*u1.y + w1*u2.x*u2.x + w2*u2.y*u2.y;
            f4 va = {u0.x, u1.y, u0.y, u2.x};
            f4 vb = {u1.x, u2.y, n0, n1};
            ldsA[i] = va; ldsB[i] = vb;
        }
        if (tid < 128) {
            const float* yb = y + (size_t)b * 3 * NQ;
            const int q = qb*128 + tid;
            const float y0 = yb[q], y1 = yb[NQ+q], y2 = yb[2*NQ+q];
            f4 qv = {-2.f*w0*y0, -2.f*w1*y1, -2.f*w2*y2,
                     w0*y0*y0 + w1*y1*y1 + w2*y2*y2};
            ldsQuad[tid] = qv;
        }
    }
    __syncthreads();

    // hoist owned points into broadcast register pairs
    const int j0 = pg * 16;
    f2 qx[16], qy[16], qz[16];
    float mm[16];
    #pragma unroll
    for (int r = 0; r < 16; ++r) {
        const f4 qv = ldsQuad[j0 + r];
        f2 bx = {qv.x, qv.x}; qx[r] = bx;
        f2 by = {qv.y, qv.y}; qy[r] = by;
        f2 bz = {qv.z, qv.z}; qz[r] = bz;
        mm[r] = FINF;
    }

    // 32 interleaved pair-steps = 64 staged points per thread
    const f4* Ap = ldsA + s;
    const f4* Bp = ldsB + s;
    #pragma unroll 4
    for (int j = 0; j < 32; ++j) {
        const f4 a  = Ap[j * nSlices];
        const f4 bb = Bp[j * nSlices];
        const f2 vx = a.xy,  vy = a.zw;
        const f2 vz = bb.xy, vn = bb.zw;
        #pragma unroll
        for (int r = 0; r < 16; ++r) {
            f2 acc = pk_fma(qx[r], vx, vn);
            acc = pk_fma(qy[r], vy, acc);
            acc = pk_fma(qz[r], vz, acc);
            mm[r] = min3f(mm[r], acc.x, acc.y);
        }
    }
    __syncthreads();   // done reading ldsA/ldsB -> reuse as scratch

    // scr[j_own * (S+1) + s]  (padded stride)
    float* scr = (float*)ldsA;
    const int SP1 = nSlices + 1;
    #pragma unroll
    for (int r = 0; r < 16; ++r) scr[(j0 + r) * SP1 + s] = mm[r];
    __syncthreads();

    // stage 1: each thread folds 16 slices of one owned point
    float* scrB = (float*)ldsB;
    {
        const int j  = tid & (nOwn - 1);
        const int s0 = tid / nOwn;              // [0, 256/nOwn)
        float v = FINF;
        #pragma unroll
        for (int k = 0; k < 16; ++k) v = fminf(v, scr[j * SP1 + s0*16 + k]);
        scrB[s0 * nOwn + j] = v;
    }
    __syncthreads();

    // stage 2: finish min, add deferred owned norm, sum owned points
    if (tid < nOwn) {
        const int nG = 256 / nOwn;
        float v = scrB[tid];
        for (int g = 1; g < nG; ++g) v = fminf(v, scrB[g * nOwn + tid]);
        v += ldsQuad[tid].w;
        for (int off = 32; off > 0; off >>= 1) v += __shfl_down(v, off);
        if ((tid & 63) == 0) wsum[tid >> 6] = v;
    }
    __syncthreads();
    if (tid == 0) blockSums[blk] = (nOwn == 128) ? (wsum[0] + wsum[1]) : wsum[0];

    // ---- last-block deterministic finish (replaces second launch) ----
    __threadfence();                       // release blockSums[blk]
    __syncthreads();
    if (tid == 0) lastFlag = (atomicAdd(cnt, 1) == 511);
    __syncthreads();
    if (!lastFlag) return;
    __threadfence();                       // acquire all blocks' sums

    // fixed index order -> identical result regardless of which block is last
    double sv = (double)blockSums[tid] * (1.0 / (NB * NP))
              + (double)blockSums[256 + tid] * (1.0 / (NB * NQ));
    for (int off = 32; off > 0; off >>= 1) sv += __shfl_down(sv, off);
    if ((tid & 63) == 0) redd[tid >> 6] = sv;
    __syncthreads();
    if (tid == 0) out[0] = (float)(redd[0] + redd[1] + redd[2] + redd[3]);
}

extern "C" void kernel_launch(void* const* d_in, const int* in_sizes, int n_in,
                              void* d_out, int out_size, void* d_ws, size_t ws_size,
                              hipStream_t stream) {
    const float* y = (const float*)d_in[0];   // [8,3,64,64]
    const float* t = (const float*)d_in[1];   // [8,2048,3]
    const float* w = (const float*)d_in[2];   // [3]
    float* out = (float*)d_out;
    float* blockSums = (float*)d_ws;          // 512 floats
    int*   cnt = (int*)(blockSums + 512);     // done-counter

    hipMemsetAsync(cnt, 0, sizeof(int), stream);
    chamfer_fused<<<512, 256, 0, stream>>>(y, t, w, blockSums, cnt, out);
}

// Round 9
// 33.654 us; speedup vs baseline: 1.5166x; 1.5166x over previous
//
#include <hip/hip_runtime.h>

#define NB 8
#define NQ 4096   // h*w
#define NP 2048
#define FINF 3.402823466e38f
#define FP_SCALE 4294967296.0   // 2^32 fixed-point for deterministic integer accumulation

typedef float f2 __attribute__((ext_vector_type(2)));
typedef float f4 __attribute__((ext_vector_type(4)));

// VOP3P packed FMA: ALL operands are 64-bit register pairs (scalar src0 does not
// assemble). Lessons R5-R8: no op_sel packing, no VGPR caps (allocator remat = 4.7x),
// no per-thread __threadfence (L2 writeback storm = 2.5x) — order via atomics only.
__device__ __forceinline__ f2 pk_fma(f2 a, f2 b, f2 c) {
    f2 d;
    asm("v_pk_fma_f32 %0, %1, %2, %3" : "=v"(d) : "v"(a), "v"(b), "v"(c));
    return d;
}
__device__ __forceinline__ float min3f(float a, float b, float c) {
    float d;
    asm("v_min3_f32 %0, %1, %2, %3" : "=v"(d) : "v"(a), "v"(b), "v"(c));
    return d;
}

// Single kernel: 512 blocks x 256 threads, 66 KB LDS -> 2 blocks/CU, all co-resident.
// Main body is EXACTLY R4's (best measured). Finish: block partial sums accumulate via
// deterministic fixed-point int64 device-scope atomics; last block (release/acquire on
// a counter, attached to the atomic ops — no standalone fences) writes the scalar.
//  blocks [0,256):   bp. b=blk>>5, pb=blk&31: owns 64 p; stages all 4096 y (2048 pairs).
//  blocks [256,512): bq. b=idx>>5, qb=idx&31: owns 128 q; stages all 2048 t (1024 pairs).
// Pair j in LDS: A[j]=(x0,x1,y0,y1), B[j]=(z0,z1,n0,n1), n = w^2-norm.
// pg owns 16 points (f2 broadcast pairs in regs), s = slice; interleaved pair index
// j*nSlices+s -> conflict-free ds_read_b128. Per 2 distances: 3 pk_fma + 1 min3.
__global__ __launch_bounds__(256) void chamfer_fused(const float* __restrict__ y,
                                                     const float* __restrict__ t,
                                                     const float* __restrict__ w,
                                                     long long* __restrict__ accBP,
                                                     long long* __restrict__ accBQ,
                                                     int* __restrict__ cnt,
                                                     float* __restrict__ out)
{
    __shared__ f4 ldsA[2048];   // 32 KB
    __shared__ f4 ldsB[2048];   // 32 KB
    __shared__ f4 ldsQuad[128]; // owned: (-2w2c0, -2w2c1, -2w2c2, norm)
    __shared__ float wsum[2];

    const int tid = threadIdx.x;
    const int blk = blockIdx.x;
    const float w0 = w[0]*w[0], w1 = w[1]*w[1], w2 = w[2]*w[2];

    int nOwn, nSlices, pg, s;

    if (blk < 256) {
        // ---- bp: own 64 p, stage 4096 y-points (2048 pairs) ----
        nOwn = 64; nSlices = 64; pg = tid & 3; s = tid >> 2;
        const int b = blk >> 5, pb = blk & 31;
        const float* yb = y + (size_t)b * 3 * NQ;
        const f2* xs = (const f2*)yb;
        const f2* ys = (const f2*)(yb + NQ);
        const f2* zs = (const f2*)(yb + 2*NQ);
        for (int i = tid; i < 2048; i += 256) {
            const f2 xp = xs[i], yp = ys[i], zp = zs[i];
            const float n0 = w0*xp.x*xp.x + w1*yp.x*yp.x + w2*zp.x*zp.x;
            const float n1 = w0*xp.y*xp.y + w1*yp.y*yp.y + w2*zp.y*zp.y;
            f4 va = {xp.x, xp.y, yp.x, yp.y};
            f4 vb = {zp.x, zp.y, n0, n1};
            ldsA[i] = va; ldsB[i] = vb;
        }
        if (tid < 64) {
            const float* tp = t + ((size_t)b * NP + pb*64 + tid) * 3;
            const float t0 = tp[0], t1 = tp[1], t2 = tp[2];
            f4 q = {-2.f*w0*t0, -2.f*w1*t1, -2.f*w2*t2,
                    w0*t0*t0 + w1*t1*t1 + w2*t2*t2};
            ldsQuad[tid] = q;
        }
    } else {
        // ---- bq: own 128 q, stage 2048 t-points (1024 pairs) ----
        nOwn = 128; nSlices = 32; pg = tid & 7; s = tid >> 3;
        const int idx = blk - 256;
        const int b = idx >> 5, qb = idx & 31;
        const float* tb = t + (size_t)b * NP * 3;
        for (int i = tid; i < 1024; i += 256) {
            const f2* tp2 = (const f2*)(tb + i*6);
            const f2 u0 = tp2[0], u1 = tp2[1], u2 = tp2[2];
            // pt0=(u0.x,u0.y,u1.x)  pt1=(u1.y,u2.x,u2.y)
            const float n0 = w0*u0.x*u0.x + w1*u0.y*u0.y + w2*u1.x*u1.x;
            const float n1 = w0*u1.y*u1.y + w1*u2.x*u2.x + w2*u2.y*u2.y;
            f4 va = {u0.x, u1.y, u0.y, u2.x};
            f4 vb = {u1.x, u2.y, n0, n1};
            ldsA[i] = va; ldsB[i] = vb;
        }
        if (tid < 128) {
            const float* yb = y + (size_t)b * 3 * NQ;
            const int q = qb*128 + tid;
            const float y0 = yb[q], y1 = yb[NQ+q], y2 = yb[2*NQ+q];
            f4 qv = {-2.f*w0*y0, -2.f*w1*y1, -2.f*w2*y2,
                     w0*y0*y0 + w1*y1*y1 + w2*y2*y2};
            ldsQuad[tid] = qv;
        }
    }
    __syncthreads();

    // hoist owned points into broadcast register pairs
    const int j0 = pg * 16;
    f2 qx[16], qy[16], qz[16];
    float mm[16];
    #pragma unroll
    for (int r = 0; r < 16; ++r) {
        const f4 qv = ldsQuad[j0 + r];
        f2 bx = {qv.x, qv.x}; qx[r] = bx;
        f2 by = {qv.y, qv.y}; qy[r] = by;
        f2 bz = {qv.z, qv.z}; qz[r] = bz;
        mm[r] = FINF;
    }

    // 32 interleaved pair-steps = 64 staged points per thread
    const f4* Ap = ldsA + s;
    const f4* Bp = ldsB + s;
    #pragma unroll 4
    for (int j = 0; j < 32; ++j) {
        const f4 a  = Ap[j * nSlices];
        const f4 bb = Bp[j * nSlices];
        const f2 vx = a.xy,  vy = a.zw;
        const f2 vz = bb.xy, vn = bb.zw;
        #pragma unroll
        for (int r = 0; r < 16; ++r) {
            f2 acc = pk_fma(qx[r], vx, vn);
            acc = pk_fma(qy[r], vy, acc);
            acc = pk_fma(qz[r], vz, acc);
            mm[r] = min3f(mm[r], acc.x, acc.y);
        }
    }
    __syncthreads();   // done reading ldsA/ldsB -> reuse as scratch

    // scr[j_own * (S+1) + s]  (padded stride)
    float* scr = (float*)ldsA;
    const int SP1 = nSlices + 1;
    #pragma unroll
    for (int r = 0; r < 16; ++r) scr[(j0 + r) * SP1 + s] = mm[r];
    __syncthreads();

    // stage 1: each thread folds 16 slices of one owned point
    float* scrB = (float*)ldsB;
    {
        const int j  = tid & (nOwn - 1);
        const int s0 = tid / nOwn;              // [0, 256/nOwn)
        float v = FINF;
        #pragma unroll
        for (int k = 0; k < 16; ++k) v = fminf(v, scr[j * SP1 + s0*16 + k]);
        scrB[s0 * nOwn + j] = v;
    }
    __syncthreads();

    // stage 2: finish min, add deferred owned norm, sum owned points
    if (tid < nOwn) {
        const int nG = 256 / nOwn;
        float v = scrB[tid];
        for (int g = 1; g < nG; ++g) v = fminf(v, scrB[g * nOwn + tid]);
        v += ldsQuad[tid].w;
        for (int off = 32; off > 0; off >>= 1) v += __shfl_down(v, off);
        if ((tid & 63) == 0) wsum[tid >> 6] = v;
    }
    __syncthreads();

    // ---- deterministic fixed-point atomic finish (single thread per block) ----
    if (tid == 0) {
        const float bsum = (nOwn == 128) ? (wsum[0] + wsum[1]) : wsum[0];
        const long long qv = __double2ll_rn((double)bsum * FP_SCALE);
        __hip_atomic_fetch_add((nOwn == 64) ? accBP : accBQ, qv,
                               __ATOMIC_RELAXED, __HIP_MEMORY_SCOPE_AGENT);
        const int old = __hip_atomic_fetch_add(cnt, 1,
                               __ATOMIC_RELEASE, __HIP_MEMORY_SCOPE_AGENT);
        if (old == 511) {
            // single acquire in the whole grid; syncs with all 511 releases
            (void)__hip_atomic_load(cnt, __ATOMIC_ACQUIRE, __HIP_MEMORY_SCOPE_AGENT);
            const long long sp = __hip_atomic_load(accBP, __ATOMIC_RELAXED, __HIP_MEMORY_SCOPE_AGENT);
            const long long sq = __hip_atomic_load(accBQ, __ATOMIC_RELAXED, __HIP_MEMORY_SCOPE_AGENT);
            out[0] = (float)((double)sp * (1.0 / FP_SCALE) * (1.0 / (NB * NP))
                           + (double)sq * (1.0 / FP_SCALE) * (1.0 / (NB * NQ)));
        }
    }
}

extern "C" void kernel_launch(void* const* d_in, const int* in_sizes, int n_in,
                              void* d_out, int out_size, void* d_ws, size_t ws_size,
                              hipStream_t stream) {
    const float* y = (const float*)d_in[0];   // [8,3,64,64]
    const float* t = (const float*)d_in[1];   // [8,2048,3]
    const float* w = (const float*)d_in[2];   // [3]
    float* out = (float*)d_out;

    long long* acc = (long long*)d_ws;        // acc[0]=bp sum, acc[1]=bq sum, acc[2] slot = cnt
    hipMemsetAsync(d_ws, 0, 3 * sizeof(long long), stream);
    chamfer_fused<<<512, 256, 0, stream>>>(y, t, w, acc, acc + 1, (int*)(acc + 2), out);
}

// Round 10
// 26.430 us; speedup vs baseline: 1.9311x; 1.2733x over previous
//
#include <hip/hip_runtime.h>

#define NB 8
#define NQ 4096   // h*w
#define NP 2048
#define FINF 3.402823466e38f

typedef float f2 __attribute__((ext_vector_type(2)));
typedef float f4 __attribute__((ext_vector_type(4)));

// VOP3P packed FMA: ALL operands are 64-bit register pairs. Session lessons:
// no scalar src0 (R5), no op_sel packing / no VGPR caps (R6/R7 remat+conflicts),
// no threadfence or release atomics for cross-block finish (R8/R9 L2-writeback storm).
__device__ __forceinline__ f2 pk_fma(f2 a, f2 b, f2 c) {
    f2 d;
    asm("v_pk_fma_f32 %0, %1, %2, %3" : "=v"(d) : "v"(a), "v"(b), "v"(c));
    return d;
}
__device__ __forceinline__ float min3f(float a, float b, float c) {
    float d;
    asm("v_min3_f32 %0, %1, %2, %3" : "=v"(d) : "v"(a), "v"(b), "v"(c));
    return d;
}

// Main: 1024 UNIFORM blocks x 256 threads, 34 KB LDS, VGPR ~128 -> 4 blocks/CU
// (16 waves/CU), all blocks co-resident. Inner loop is byte-identical to R4's
// (best measured), only the staged set is halved.
//  blocks [0,512):    bp. blk=(b*32+pt)*2+half: owns 64 p (pt), stages one y-half
//                     (1024 pairs). Output: 64 PARTIAL row-mins (+norm) -> ws[blk*64..].
//  blocks [512,1024): bq. idx=blk-512, b=idx>>6, qt=idx&63: owns 64 q, stages ALL
//                     2048 t (1024 pairs). Output: complete mins summed -> ws[32768+idx].
// Pair j in LDS: A[j]=(x0,x1,y0,y1), B[j]=(z0,z1,n0,n1), n = w^2-norm.
// pg=tid&3 owns 16 points (f2 broadcast pairs in regs); s=tid>>2 is the slice;
// pair index j*64+s -> 16 consecutive f4 slots per wave, 4-lane broadcast each:
// conflict-free ds_read_b128 with immediate offsets (j*1024B).
// Per 2 distances: 3 pk_fma + 1 min3 (owned norm deferred to epilogue).
__global__ __launch_bounds__(256) void chamfer_main(const float* __restrict__ y,
                                                    const float* __restrict__ t,
                                                    const float* __restrict__ w,
                                                    float* __restrict__ ws)
{
    // single contiguous LDS block: A[1024] | B[1024] | quad[64] | scrB(256 f)
    // (scr scratch needs 64*65=4160 floats -> must span A+B contiguously)
    __shared__ f4 lds4[1024 + 1024 + 64 + 64];
    f4* ldsA = lds4;
    f4* ldsB = lds4 + 1024;
    f4* quad = lds4 + 2048;
    float* scr  = (float*)lds4;                 // 8192 floats available
    float* scrB = (float*)(lds4 + 2048 + 64);   // 256 floats

    const int tid = threadIdx.x;
    const int blk = blockIdx.x;
    const int pg  = tid & 3;
    const int s   = tid >> 2;
    const float w0 = w[0]*w[0], w1 = w[1]*w[1], w2 = w[2]*w[2];
    const bool isBQ = blk >= 512;

    if (!isBQ) {
        // ---- bp: own 64 p, stage one y-half (1024 pairs = 2048 q-points) ----
        const int b = blk >> 6, pt = (blk >> 1) & 31, half = blk & 1;
        const float* yb = y + (size_t)b * 3 * NQ + half * 2048;
        const f2* xs = (const f2*)yb;
        const f2* ys = (const f2*)(yb + NQ);
        const f2* zs = (const f2*)(yb + 2*NQ);
        for (int i = tid; i < 1024; i += 256) {
            const f2 xp = xs[i], yp = ys[i], zp = zs[i];
            const float n0 = w0*xp.x*xp.x + w1*yp.x*yp.x + w2*zp.x*zp.x;
            const float n1 = w0*xp.y*xp.y + w1*yp.y*yp.y + w2*zp.y*zp.y;
            f4 va = {xp.x, xp.y, yp.x, yp.y};
            f4 vb = {zp.x, zp.y, n0, n1};
            ldsA[i] = va; ldsB[i] = vb;
        }
        if (tid < 64) {
            const float* tp = t + ((size_t)b * NP + pt*64 + tid) * 3;
            const float t0 = tp[0], t1 = tp[1], t2 = tp[2];
            f4 q = {-2.f*w0*t0, -2.f*w1*t1, -2.f*w2*t2,
                    w0*t0*t0 + w1*t1*t1 + w2*t2*t2};
            quad[tid] = q;
        }
    } else {
        // ---- bq: own 64 q, stage all 2048 t-points (1024 pairs) ----
        const int idx = blk - 512;
        const int b = idx >> 6, qt = idx & 63;
        const float* tb = t + (size_t)b * NP * 3;
        for (int i = tid; i < 1024; i += 256) {
            const f2* tp2 = (const f2*)(tb + i*6);
            const f2 u0 = tp2[0], u1 = tp2[1], u2 = tp2[2];
            // pt0=(u0.x,u0.y,u1.x)  pt1=(u1.y,u2.x,u2.y)
            const float n0 = w0*u0.x*u0.x + w1*u0.y*u0.y + w2*u1.x*u1.x;
            const float n1 = w0*u1.y*u1.y + w1*u2.x*u2.x + w2*u2.y*u2.y;
            f4 va = {u0.x, u1.y, u0.y, u2.x};
            f4 vb = {u1.x, u2.y, n0, n1};
            ldsA[i] = va; ldsB[i] = vb;
        }
        if (tid < 64) {
            const float* yb = y + (size_t)b * 3 * NQ;
            const int q = qt*64 + tid;
            const float y0 = yb[q], y1 = yb[NQ+q], y2 = yb[2*NQ+q];
            f4 qv = {-2.f*w0*y0, -2.f*w1*y1, -2.f*w2*y2,
                     w0*y0*y0 + w1*y1*y1 + w2*y2*y2};
            quad[tid] = qv;
        }
    }
    __syncthreads();

    // hoist owned points into broadcast register pairs (R4-identical)
    const int j0 = pg * 16;
    f2 qx[16], qy[16], qz[16];
    float mm[16];
    #pragma unroll
    for (int r = 0; r < 16; ++r) {
        const f4 qv = quad[j0 + r];
        f2 bx = {qv.x, qv.x}; qx[r] = bx;
        f2 by = {qv.y, qv.y}; qy[r] = by;
        f2 bz = {qv.z, qv.z}; qz[r] = bz;
        mm[r] = FINF;
    }

    // 16 interleaved pair-steps = 32 staged points per thread
    const f4* Ap = ldsA + s;
    const f4* Bp = ldsB + s;
    #pragma unroll 4
    for (int j = 0; j < 16; ++j) {
        const f4 a  = Ap[j * 64];          // imm offset j*1024B, conflict-free
        const f4 bb = Bp[j * 64];
        const f2 vx = a.xy,  vy = a.zw;
        const f2 vz = bb.xy, vn = bb.zw;
        #pragma unroll
        for (int r = 0; r < 16; ++r) {
            f2 acc = pk_fma(qx[r], vx, vn);
            acc = pk_fma(qy[r], vy, acc);
            acc = pk_fma(qz[r], vz, acc);
            mm[r] = min3f(mm[r], acc.x, acc.y);
        }
    }
    __syncthreads();   // done reading ldsA/ldsB -> reuse as scratch

    // scr[j_own * 65 + s]  (padded stride, conflict-free)
    #pragma unroll
    for (int r = 0; r < 16; ++r) scr[(j0 + r) * 65 + s] = mm[r];
    __syncthreads();

    // stage 1: each thread folds 16 slices of one owned point
    {
        const int j  = tid & 63;
        const int s0 = tid >> 6;               // [0,4)
        float v = FINF;
        #pragma unroll
        for (int k = 0; k < 16; ++k) v = fminf(v, scr[j * 65 + s0*16 + k]);
        scrB[s0 * 64 + j] = v;
    }
    __syncthreads();

    // stage 2: finish min, add deferred owned norm, emit
    if (tid < 64) {
        float v = fminf(fminf(scrB[tid], scrB[64+tid]),
                        fminf(scrB[128+tid], scrB[192+tid]))
                + quad[tid].w;
        if (!isBQ) {
            ws[blk*64 + tid] = v;              // partial row-min (one y-half)
        } else {
            for (int off = 32; off > 0; off >>= 1) v += __shfl_down(v, off);
            if (tid == 0) ws[32768 + (blk - 512)] = v;   // complete, summed
        }
    }
}

// Single-block deterministic finish: merge bp halves, two means, scalar out.
// (proven in R7)
__global__ __launch_bounds__(1024) void chamfer_reduce(const float* __restrict__ ws,
                                                       float* __restrict__ out)
{
    const int tid = threadIdx.x;
    double sbp = 0.0, sbq = 0.0;
    for (int i = tid; i < 16384; i += 1024) {      // k = b*32+pt in [0,256), j in [0,64)
        const int k = i >> 6, j = i & 63;
        sbp += (double)fminf(ws[k*128 + j], ws[k*128 + 64 + j]);
    }
    if (tid < 512) sbq = (double)ws[32768 + tid];
    double sv = sbp * (1.0 / (NB * NP)) + sbq * (1.0 / (NB * NQ));

    for (int off = 32; off > 0; off >>= 1) sv += __shfl_down(sv, off);

    __shared__ double redd[16];
    if ((tid & 63) == 0) redd[tid >> 6] = sv;
    __syncthreads();
    if (tid == 0) {
        double tot = 0.0;
        #pragma unroll
        for (int i = 0; i < 16; ++i) tot += redd[i];
        out[0] = (float)tot;
    }
}

extern "C" void kernel_launch(void* const* d_in, const int* in_sizes, int n_in,
                              void* d_out, int out_size, void* d_ws, size_t ws_size,
                              hipStream_t stream) {
    const float* y = (const float*)d_in[0];   // [8,3,64,64]
    const float* t = (const float*)d_in[1];   // [8,2048,3]
    const float* w = (const float*)d_in[2];   // [3]
    float* out = (float*)d_out;
    float* ws  = (float*)d_ws;                // [0,32768) bp partials | [32768,33280) bq sums

    chamfer_main<<<1024, 256, 0, stream>>>(y, t, w, ws);
    chamfer_reduce<<<1, 1024, 0, stream>>>(ws, out);
}